// Round 5
// baseline (454.916 us; speedup 1.0000x reference)
//
#include <hip/hip_runtime.h>

// B=2, T=2048, C=2048, H=16, HD=128, P=256
// s=mean|W| -> WT ternary bf16 [n][k] -> dbuf single-barrier bf16 GEMMs
//   (Q,K: rope fused in epilogue; V: transposed write) -> 2-blocks/CU folded flash -> out GEMM

typedef __attribute__((ext_vector_type(8))) short short8;
typedef __attribute__((ext_vector_type(4))) float f32x4;
typedef unsigned short u16;
typedef unsigned int u32;

__device__ __forceinline__ float bf2f(u16 u) {
    u32 x = ((u32)u) << 16;
    return __builtin_bit_cast(float, x);
}
__device__ __forceinline__ u16 f2bf(float f) {
    u32 x = __builtin_bit_cast(u32, f);
    x += 0x7fffu + ((x >> 16) & 1u);   // RNE
    return (u16)(x >> 16);
}
__device__ __forceinline__ u16 f2bf_trunc(float f) {
    return (u16)(__builtin_bit_cast(u32, f) >> 16);
}
__device__ __forceinline__ u32 pack2(u16 a, u16 b) { return (u32)a | ((u32)b << 16); }

__device__ __forceinline__ void async16(const void* g, void* l) {
    __builtin_amdgcn_global_load_lds((const __attribute__((address_space(1))) u32*)g,
                                     (__attribute__((address_space(3))) u32*)l, 16, 0, 0);
}

__device__ const int d_OCT_IDX[8][8] = {
    {0,1,2,3,4,5,6,7},{1,0,3,2,5,4,7,6},{2,3,0,1,6,7,4,5},{3,2,1,0,7,6,5,4},
    {4,5,6,7,0,1,2,3},{5,4,7,6,1,0,3,2},{6,7,4,5,2,3,0,1},{7,6,5,4,3,2,1,0}};
__device__ const float d_OCT_SIGN[8][8] = {
    { 1, 1, 1, 1, 1, 1, 1, 1},{ 1,-1, 1,-1, 1,-1,-1, 1},{ 1,-1,-1, 1, 1, 1,-1,-1},
    { 1, 1,-1,-1, 1,-1, 1,-1},{ 1,-1,-1,-1,-1, 1, 1, 1},{ 1, 1,-1, 1,-1,-1,-1, 1},
    { 1, 1, 1,-1,-1, 1,-1,-1},{ 1,-1, 1, 1,-1,-1, 1,-1}};

// ---- stage 1: 64 partial |W| sums per weight ----
__global__ __launch_bounds__(256) void reduce1_kernel(
    const float* __restrict__ w0, const float* __restrict__ w1,
    const float* __restrict__ w2, const float* __restrict__ w3,
    float* __restrict__ partials) {
    int bid = blockIdx.x, wsel = bid >> 6, part = bid & 63;
    const float* W = wsel == 0 ? w0 : wsel == 1 ? w1 : wsel == 2 ? w2 : w3;
    int base = part * 8192 + threadIdx.x;
    float acc = 0.f;
#pragma unroll
    for (int k = 0; k < 32; k++) acc += fabsf(W[base + k * 256]);
#pragma unroll
    for (int off = 1; off < 64; off <<= 1) acc += __shfl_xor(acc, off, 64);
    __shared__ float r4[4];
    if ((threadIdx.x & 63) == 0) r4[threadIdx.x >> 6] = acc;
    __syncthreads();
    if (threadIdx.x == 0) partials[bid] = r4[0] + r4[1] + r4[2] + r4[3];
}
__global__ __launch_bounds__(256) void reduce2_kernel(const float* __restrict__ partials,
                                                      float* __restrict__ s_vals) {
    int w = threadIdx.x >> 6, lane = threadIdx.x & 63;
    float v = partials[w * 64 + lane];
#pragma unroll
    for (int off = 1; off < 64; off <<= 1) v += __shfl_xor(v, off, 64);
    if (lane == 0) s_vals[w] = v / 524288.0f + 1e-8f;
}

// ---- x (f32) -> bf16 ----
__global__ __launch_bounds__(256) void cast_bf16_kernel(const float* __restrict__ X, u16* __restrict__ Xb) {
    int gid = blockIdx.x * 256 + threadIdx.x;
    const float4* X4 = (const float4*)X;
    float4 a = X4[gid * 2], b = X4[gid * 2 + 1];
    uint4 o;
    o.x = pack2(f2bf(a.x), f2bf(a.y));
    o.y = pack2(f2bf(a.z), f2bf(a.w));
    o.z = pack2(f2bf(b.x), f2bf(b.y));
    o.w = pack2(f2bf(b.z), f2bf(b.w));
    *(uint4*)&Xb[gid * 8] = o;
}

// ---- WT[n][k]: coalesced via LDS 64x64 tile transpose ----
__global__ __launch_bounds__(256) void build_weff_kernel(
    const float* __restrict__ W, const float* __restrict__ sptr, u16* __restrict__ WT) {
    __shared__ float Tt[64 * 68];
    int tid = threadIdx.x;
    int combo = blockIdx.x >> 4, sub = blockIdx.x & 15;
    int j = combo >> 3, kblk = combo & 7;
    int i = 0;
#pragma unroll
    for (int ii = 0; ii < 8; ii++)
        if (d_OCT_IDX[ii][j] == kblk) i = ii;
    float sign = d_OCT_SIGN[i][j];
    int p0 = (sub >> 2) * 64, q0 = (sub & 3) * 64;
    float inv_s = 1.0f / (*sptr);
#pragma unroll
    for (int pass = 0; pass < 4; pass++) {
        int p = p0 + pass * 16 + (tid >> 4);
        int q = q0 + (tid & 15) * 4;
        float4 wv = *(const float4*)&W[i * 65536 + p * 256 + q];
        float* Tp = &Tt[(pass * 16 + (tid >> 4)) * 68 + (tid & 15) * 4];
        Tp[0] = sign * rintf(fminf(1.f, fmaxf(-1.f, wv.x * inv_s)));
        Tp[1] = sign * rintf(fminf(1.f, fmaxf(-1.f, wv.y * inv_s)));
        Tp[2] = sign * rintf(fminf(1.f, fmaxf(-1.f, wv.z * inv_s)));
        Tp[3] = sign * rintf(fminf(1.f, fmaxf(-1.f, wv.w * inv_s)));
    }
    __syncthreads();
#pragma unroll
    for (int pass = 0; pass < 2; pass++) {
        int qq = pass * 32 + (tid >> 3);
        int pl = (tid & 7) * 8;
        u16 r[8];
#pragma unroll
        for (int l = 0; l < 8; l++) r[l] = f2bf_trunc(Tt[(pl + l) * 68 + qq]);
        uint4 o;
        o.x = pack2(r[0], r[1]); o.y = pack2(r[2], r[3]);
        o.z = pack2(r[4], r[5]); o.w = pack2(r[6], r[7]);
        *(uint4*)&WT[(size_t)(kblk * 256 + q0 + qq) * 2048 + j * 256 + p0 + pl] = o;
    }
}

// ---- GEMM: C[4096][2048] = s*(A @ WT^T); single-barrier double-buffered K-loop ----
// MODE 0: rope fused, bf16 row-major (rscale folds sm*log2e for Q, 1.0 for K)
// MODE 1: f32 row-major.  MODE 2: bf16 VT[(b*16+h)*128+d][t]
template <int MODE>
__global__ __launch_bounds__(256) void gemm_kernel(
    const u16* __restrict__ A, const u16* __restrict__ Bt,
    const float* __restrict__ sptr, const float* __restrict__ fc,
    const float* __restrict__ fs, float rscale, void* __restrict__ Cout) {
    __shared__ __align__(16) u16 As[2][128 * 32];
    __shared__ __align__(16) u16 Bs[2][128 * 32];
    const int K = 2048;
    int tid = threadIdx.x, lane = tid & 63, wid = tid >> 6;
    int quad = lane >> 4, l16 = lane & 15;
    int wm = (wid >> 1) * 64, wn = (wid & 1) * 64;
    int m0 = blockIdx.y * 128, n0 = blockIdx.x * 128;
    f32x4 acc[4][4];
#pragma unroll
    for (int a = 0; a < 4; a++)
#pragma unroll
        for (int b = 0; b < 4; b++) acc[a][b] = (f32x4){0.f, 0.f, 0.f, 0.f};
    int srow = lane >> 2;                    // 0..15: row within 16-row chunk
    int sblk = (lane & 3) ^ (srow & 3);      // source-side swizzle
    const u16* Ag = A + (size_t)(m0 + wid * 32 + srow) * K + sblk * 8;
    const u16* Bg = Bt + (size_t)(n0 + wid * 32 + srow) * K + sblk * 8;
    int rblk = (quad ^ (l16 & 3)) * 8;       // read-side swizzle
#define GSTAGE(k0_, buf_)                                              \
    do {                                                               \
        async16(Ag + (k0_), &As[buf_][wid * 1024]);                    \
        async16(Ag + (k0_) + (size_t)16 * K, &As[buf_][wid * 1024 + 512]); \
        async16(Bg + (k0_), &Bs[buf_][wid * 1024]);                    \
        async16(Bg + (k0_) + (size_t)16 * K, &Bs[buf_][wid * 1024 + 512]); \
    } while (0)
    GSTAGE(0, 0);
    for (int it = 0; it < K / 32; it++) {
        int c = it & 1;
        __syncthreads();   // drains prefetch issued one full iter ago; orders buf reuse
        if (it + 1 < K / 32) GSTAGE((it + 1) * 32, 1 - c);
        short8 af[4], bfv[4];
#pragma unroll
        for (int mt = 0; mt < 4; mt++) af[mt] = *(const short8*)&As[c][(wm + mt * 16 + l16) * 32 + rblk];
#pragma unroll
        for (int nt = 0; nt < 4; nt++) bfv[nt] = *(const short8*)&Bs[c][(wn + nt * 16 + l16) * 32 + rblk];
#pragma unroll
        for (int mt = 0; mt < 4; mt++)
#pragma unroll
            for (int nt = 0; nt < 4; nt++)
                acc[mt][nt] = __builtin_amdgcn_mfma_f32_16x16x32_bf16(af[mt], bfv[nt], acc[mt][nt], 0, 0, 0);
    }
#undef GSTAGE
    float s = *sptr;
#pragma unroll
    for (int mt = 0; mt < 4; mt++)
#pragma unroll
        for (int nt = 0; nt < 4; nt++) {
            int mg = m0 + wm + mt * 16 + quad * 4;   // +r ; C/D row=quad*4+reg
            int ng = n0 + wn + nt * 16 + l16;        // col=lane&15
            if (MODE == 0) {
                int mi = (ng & 127) >> 1;
#pragma unroll
                for (int r = 0; r < 4; r++) {
                    float v = acc[mt][nt][r] * s;
                    float vp = __shfl_xor(v, 1, 64);  // partner column (ng^1): lane^1
                    int t = mg + r;
                    int tm = t & 2047;                // position within batch (fc/fs are [2048][64])
                    float cs = fc[tm * 64 + mi] * rscale;
                    float sn = fs[tm * 64 + mi] * rscale;
                    if (!(ng & 1)) {   // even lane stores the pair as one dword
                        u32 pk = pack2(f2bf(v * cs - vp * sn), f2bf(v * sn + vp * cs));
                        ((u32*)Cout)[((size_t)t * 2048 + ng) >> 1] = pk;
                    }
                }
            } else if (MODE == 1) {
#pragma unroll
                for (int r = 0; r < 4; r++)
                    ((float*)Cout)[(size_t)(mg + r) * 2048 + ng] = acc[mt][nt][r] * s;
            } else {
                ushort4 o4;
                o4.x = f2bf(acc[mt][nt][0] * s);
                o4.y = f2bf(acc[mt][nt][1] * s);
                o4.z = f2bf(acc[mt][nt][2] * s);
                o4.w = f2bf(acc[mt][nt][3] * s);
                *(ushort4*)&((u16*)Cout)[((size_t)((mg >> 11) * 16 + (ng >> 7)) * 128 + (ng & 127)) * 2048 + (mg & 2047)] = o4;
            }
        }
}

// ---- folded flash, 64-row Q tiles, 4 waves, 2 blocks/CU, all blocks 33 iters ----
// Q,K row-major (Q pre-scaled+roped); VT [(b*16+h)*128+d][t]; Y row-major bf16 (aliases Q)
__global__ __launch_bounds__(256, 2) void flash_kernel(
    const u16* __restrict__ Q, const u16* __restrict__ Kg,
    const u16* __restrict__ VTg, u16* __restrict__ Y) {
    __shared__ __align__(16) u16 Ks[2][64 * 128];   // [key][d], XOR-swizzled (16 KB each)
    __shared__ __align__(16) u16 Vs[2][128 * 64];   // [d][key], XOR-swizzled (16 KB each)
    __shared__ __align__(16) u16 Ps[4 * 16 * 64];   // wave-private P (8 KB)
    const int NIT = 33;
    int tid = threadIdx.x, lane = tid & 63, wid = tid >> 6;   // 4 waves
    int quad = lane >> 4, l16 = lane & 15;
    int bh = blockIdx.x, b = bh >> 4, h = bh & 15;            // x=bh: head's K/V pinned to one XCD
    int pr = blockIdx.y;                                      // 0..15 -> tile pair (pr, 31-pr)
    int nitA = pr + 1;
    const u16* Qb = Q + (size_t)b * 2048 * 2048 + h * 128;
    const u16* Kb = Kg + (size_t)b * 2048 * 2048 + h * 128;
    const u16* Vb = VTg + (size_t)bh * 128 * 2048;
    int q0 = pr * 64, nit = nitA;
    int krow = lane >> 4, kblk = lane & 15;   // K chunk: 4 rows x 16 blocks
    int vrow = lane >> 3, vblk = lane & 7;    // V chunk: 8 rows x 8 blocks
    // prologue: key tile 0 -> buf 0
#pragma unroll
    for (int cc = 0; cc < 4; cc++) {
        int ch = wid * 4 + cc;
        int kr = ch * 4 + krow;
        async16(&Kb[(size_t)kr * 2048 + (kblk ^ (kr & 15)) * 8], &Ks[0][ch * 512]);
        int vd = ch * 8 + vrow;
        async16(&Vb[(size_t)vd * 2048 + (vblk ^ (vd & 7)) * 8], &Vs[0][ch * 512]);
    }
    short8 qf[4];
#pragma unroll
    for (int kt = 0; kt < 4; kt++)
        qf[kt] = *(const short8*)&Qb[(size_t)(q0 + wid * 16 + l16) * 2048 + kt * 32 + quad * 8];
    f32x4 o[8];
#pragma unroll
    for (int nt = 0; nt < 8; nt++) o[nt] = (f32x4){0.f, 0.f, 0.f, 0.f};
    float m_[4] = {-1e30f, -1e30f, -1e30f, -1e30f};
    float l_[4] = {0.f, 0.f, 0.f, 0.f};
    int il = 0;
    for (int g = 0; g < NIT; g++) {
        int c = g & 1;
        __syncthreads();   // drains prefetch issued one full iter ago; orders buf reuse
        if (g + 1 < NIT) {
            int gn = g + 1;
            int s0n = (gn < nitA ? gn : gn - nitA) * 64;
#pragma unroll
            for (int cc = 0; cc < 4; cc++) {
                int ch = wid * 4 + cc;
                int kr = ch * 4 + krow;
                async16(&Kb[(size_t)(s0n + kr) * 2048 + (kblk ^ (kr & 15)) * 8], &Ks[1 - c][ch * 512]);
                int vd = ch * 8 + vrow;
                async16(&Vb[(size_t)vd * 2048 + s0n + (vblk ^ (vd & 7)) * 8], &Vs[1 - c][ch * 512]);
            }
        }
        int s0 = il * 64;
        // S = Q K^T : wave 16 q-rows x 64 keys
        f32x4 sc[4];
#pragma unroll
        for (int ct = 0; ct < 4; ct++) {
            f32x4 a = (f32x4){0.f, 0.f, 0.f, 0.f};
#pragma unroll
            for (int kt = 0; kt < 4; kt++) {
                short8 bfv = *(const short8*)&Ks[c][(ct * 16 + l16) * 128 + ((kt * 4 + quad) ^ l16) * 8];
                a = __builtin_amdgcn_mfma_f32_16x16x32_bf16(qf[kt], bfv, a, 0, 0, 0);
            }
            sc[ct] = a;
        }
        if (il == nit - 1) {   // diagonal tile
#pragma unroll
            for (int ct = 0; ct < 4; ct++) {
                int colg = s0 + ct * 16 + l16;
#pragma unroll
                for (int r = 0; r < 4; r++) {
                    int rowg = q0 + wid * 16 + quad * 4 + r;
                    if (colg > rowg) sc[ct][r] = -1e30f;
                }
            }
        }
        float alpha[4];
#pragma unroll
        for (int r = 0; r < 4; r++) {
            float mx = fmaxf(fmaxf(sc[0][r], sc[1][r]), fmaxf(sc[2][r], sc[3][r]));
#pragma unroll
            for (int off = 1; off < 16; off <<= 1) mx = fmaxf(mx, __shfl_xor(mx, off, 64));
            float mn = fmaxf(m_[r], mx);
            float al = exp2f(m_[r] - mn);
            float rs = 0.f;
#pragma unroll
            for (int ct = 0; ct < 4; ct++) {
                float p = exp2f(sc[ct][r] - mn);
                sc[ct][r] = p;
                rs += p;
            }
#pragma unroll
            for (int off = 1; off < 16; off <<= 1) rs += __shfl_xor(rs, off, 64);
            m_[r] = mn;
            l_[r] = l_[r] * al + rs;
            alpha[r] = al;
        }
        // P: C-layout -> wave-private LDS (in-wave lgkm ordering, no barrier)
        u16* Pw = &Ps[wid * 1024];
#pragma unroll
        for (int ct = 0; ct < 4; ct++)
#pragma unroll
            for (int r = 0; r < 4; r++) {
                int lr = quad * 4 + r;
                int key = ct * 16 + l16;
                Pw[lr * 64 + ((key >> 3) ^ (lr & 7)) * 8 + (key & 7)] = f2bf_trunc(sc[ct][r]);
            }
#pragma unroll
        for (int nt = 0; nt < 8; nt++)
#pragma unroll
            for (int r = 0; r < 4; r++) o[nt][r] *= alpha[r];
        // O += P V
#pragma unroll
        for (int kt2 = 0; kt2 < 2; kt2++) {
            short8 pa = *(const short8*)&Pw[l16 * 64 + ((kt2 * 4 + quad) ^ (l16 & 7)) * 8];
#pragma unroll
            for (int nt = 0; nt < 8; nt++) {
                short8 vb = *(const short8*)&Vs[c][(nt * 16 + l16) * 64 + ((kt2 * 4 + quad) ^ (l16 & 7)) * 8];
                o[nt] = __builtin_amdgcn_mfma_f32_16x16x32_bf16(pa, vb, o[nt], 0, 0, 0);
            }
        }
        il++;
        if (il == nit && g + 1 < NIT) {   // flush sub-problem A, switch to B
            float iv[4];
#pragma unroll
            for (int r = 0; r < 4; r++) iv[r] = 1.f / l_[r];
#pragma unroll
            for (int nt = 0; nt < 8; nt++)
#pragma unroll
                for (int r = 0; r < 4; r++) {
                    int t_ = q0 + wid * 16 + quad * 4 + r;
                    Y[((size_t)(b * 2048 + t_)) * 2048 + h * 128 + nt * 16 + l16] = f2bf(o[nt][r] * iv[r]);
                }
            q0 = (31 - pr) * 64;
            nit = NIT - nitA;
            il = 0;
#pragma unroll
            for (int kt = 0; kt < 4; kt++)
                qf[kt] = *(const short8*)&Qb[(size_t)(q0 + wid * 16 + l16) * 2048 + kt * 32 + quad * 8];
#pragma unroll
            for (int nt = 0; nt < 8; nt++) o[nt] = (f32x4){0.f, 0.f, 0.f, 0.f};
#pragma unroll
            for (int r = 0; r < 4; r++) { m_[r] = -1e30f; l_[r] = 0.f; }
        }
    }
    float iv[4];
#pragma unroll
    for (int r = 0; r < 4; r++) iv[r] = 1.f / l_[r];
#pragma unroll
    for (int nt = 0; nt < 8; nt++)
#pragma unroll
        for (int r = 0; r < 4; r++) {
            int t_ = q0 + wid * 16 + quad * 4 + r;
            Y[((size_t)(b * 2048 + t_)) * 2048 + h * 128 + nt * 16 + l16] = f2bf(o[nt][r] * iv[r]);
        }
}

extern "C" void kernel_launch(void* const* d_in, const int* in_sizes, int n_in,
                              void* d_out, int out_size, void* d_ws, size_t ws_size,
                              hipStream_t stream) {
    const float* x  = (const float*)d_in[0];
    const float* wq = (const float*)d_in[1];
    const float* wk = (const float*)d_in[2];
    const float* wv = (const float*)d_in[3];
    const float* wo = (const float*)d_in[4];
    const float* fc = (const float*)d_in[5];
    const float* fs = (const float*)d_in[6];
    float* out = (float*)d_out;

    char* ws = (char*)d_ws;
    float* s_vals   = (float*)ws;
    float* partials = (float*)(ws + 1024);
    u16* WT  = (u16*)(ws + 8192);
    u16* xb  = (u16*)(ws + 8192 + 8388608);
    u16* Qb  = xb + 8388608;
    u16* Kb  = Qb + 8388608;
    u16* VTb = Kb + 8388608;

    const float QSCALE = 0.08838834764831845f * 1.4426950408889634f;  // 1/sqrt(128)*log2(e)

    reduce1_kernel<<<256, 256, 0, stream>>>(wq, wk, wv, wo, partials);
    reduce2_kernel<<<1, 256, 0, stream>>>(partials, s_vals);
    cast_bf16_kernel<<<4096, 256, 0, stream>>>(x, xb);

    build_weff_kernel<<<1024, 256, 0, stream>>>(wq, s_vals + 0, WT);
    gemm_kernel<0><<<dim3(16, 32), 256, 0, stream>>>(xb, WT, s_vals + 0, fc, fs, QSCALE, Qb);

    build_weff_kernel<<<1024, 256, 0, stream>>>(wk, s_vals + 1, WT);
    gemm_kernel<0><<<dim3(16, 32), 256, 0, stream>>>(xb, WT, s_vals + 1, fc, fs, 1.0f, Kb);

    build_weff_kernel<<<1024, 256, 0, stream>>>(wv, s_vals + 2, WT);
    gemm_kernel<2><<<dim3(16, 32), 256, 0, stream>>>(xb, WT, s_vals + 2, fc, fs, 0.f, VTb);

    flash_kernel<<<dim3(32, 16), 256, 0, stream>>>(Qb, Kb, VTb, Qb /* Y aliases Q: disjoint rows */);

    build_weff_kernel<<<1024, 256, 0, stream>>>(wo, s_vals + 3, WT);
    gemm_kernel<1><<<dim3(16, 32), 256, 0, stream>>>(Qb, WT, s_vals + 3, fc, fs, 0.f, (void*)out);
}

// Round 7
// 439.650 us; speedup vs baseline: 1.0347x; 1.0347x over previous
//
#include <hip/hip_runtime.h>

// B=2, T=2048, C=2048, H=16, HD=128, P=256
// s=mean|W| -> WT ternary bf16 [n][k] -> 2-barrier bf16 GEMMs (Q,K: rope fused; V: transposed)
// -> flash: 128-row Q tiles, 4 waves x 32 rows, dbuf K/V, wave-private P -> out GEMM

typedef __attribute__((ext_vector_type(8))) short short8;
typedef __attribute__((ext_vector_type(4))) float f32x4;
typedef unsigned short u16;
typedef unsigned int u32;

__device__ __forceinline__ float bf2f(u16 u) {
    u32 x = ((u32)u) << 16;
    return __builtin_bit_cast(float, x);
}
__device__ __forceinline__ u16 f2bf(float f) {
    u32 x = __builtin_bit_cast(u32, f);
    x += 0x7fffu + ((x >> 16) & 1u);   // RNE
    return (u16)(x >> 16);
}
__device__ __forceinline__ u16 f2bf_trunc(float f) {
    return (u16)(__builtin_bit_cast(u32, f) >> 16);
}
__device__ __forceinline__ u32 pack2(u16 a, u16 b) { return (u32)a | ((u32)b << 16); }

__device__ __forceinline__ void async16(const void* g, void* l) {
    __builtin_amdgcn_global_load_lds((const __attribute__((address_space(1))) u32*)g,
                                     (__attribute__((address_space(3))) u32*)l, 16, 0, 0);
}

__device__ const int d_OCT_IDX[8][8] = {
    {0,1,2,3,4,5,6,7},{1,0,3,2,5,4,7,6},{2,3,0,1,6,7,4,5},{3,2,1,0,7,6,5,4},
    {4,5,6,7,0,1,2,3},{5,4,7,6,1,0,3,2},{6,7,4,5,2,3,0,1},{7,6,5,4,3,2,1,0}};
__device__ const float d_OCT_SIGN[8][8] = {
    { 1, 1, 1, 1, 1, 1, 1, 1},{ 1,-1, 1,-1, 1,-1,-1, 1},{ 1,-1,-1, 1, 1, 1,-1,-1},
    { 1, 1,-1,-1, 1,-1, 1,-1},{ 1,-1,-1,-1,-1, 1, 1, 1},{ 1, 1,-1, 1,-1,-1,-1, 1},
    { 1, 1, 1,-1,-1, 1,-1,-1},{ 1,-1, 1, 1,-1,-1, 1,-1}};

// ---- stage 1: 64 partial |W| sums per weight ----
__global__ __launch_bounds__(256) void reduce1_kernel(
    const float* __restrict__ w0, const float* __restrict__ w1,
    const float* __restrict__ w2, const float* __restrict__ w3,
    float* __restrict__ partials) {
    int bid = blockIdx.x, wsel = bid >> 6, part = bid & 63;
    const float* W = wsel == 0 ? w0 : wsel == 1 ? w1 : wsel == 2 ? w2 : w3;
    int base = part * 8192 + threadIdx.x;
    float acc = 0.f;
#pragma unroll
    for (int k = 0; k < 32; k++) acc += fabsf(W[base + k * 256]);
#pragma unroll
    for (int off = 1; off < 64; off <<= 1) acc += __shfl_xor(acc, off, 64);
    __shared__ float r4[4];
    if ((threadIdx.x & 63) == 0) r4[threadIdx.x >> 6] = acc;
    __syncthreads();
    if (threadIdx.x == 0) partials[bid] = r4[0] + r4[1] + r4[2] + r4[3];
}
__global__ __launch_bounds__(256) void reduce2_kernel(const float* __restrict__ partials,
                                                      float* __restrict__ s_vals) {
    int w = threadIdx.x >> 6, lane = threadIdx.x & 63;
    float v = partials[w * 64 + lane];
#pragma unroll
    for (int off = 1; off < 64; off <<= 1) v += __shfl_xor(v, off, 64);
    if (lane == 0) s_vals[w] = v / 524288.0f + 1e-8f;
}

// ---- x (f32) -> bf16 ----
__global__ __launch_bounds__(256) void cast_bf16_kernel(const float* __restrict__ X, u16* __restrict__ Xb) {
    int gid = blockIdx.x * 256 + threadIdx.x;
    const float4* X4 = (const float4*)X;
    float4 a = X4[gid * 2], b = X4[gid * 2 + 1];
    uint4 o;
    o.x = pack2(f2bf(a.x), f2bf(a.y));
    o.y = pack2(f2bf(a.z), f2bf(a.w));
    o.z = pack2(f2bf(b.x), f2bf(b.y));
    o.w = pack2(f2bf(b.z), f2bf(b.w));
    *(uint4*)&Xb[gid * 8] = o;
}

// ---- WT[n][k]: coalesced via LDS 64x64 tile transpose ----
__global__ __launch_bounds__(256) void build_weff_kernel(
    const float* __restrict__ W, const float* __restrict__ sptr, u16* __restrict__ WT) {
    __shared__ float Tt[64 * 68];
    int tid = threadIdx.x;
    int combo = blockIdx.x >> 4, sub = blockIdx.x & 15;
    int j = combo >> 3, kblk = combo & 7;
    int i = 0;
#pragma unroll
    for (int ii = 0; ii < 8; ii++)
        if (d_OCT_IDX[ii][j] == kblk) i = ii;
    float sign = d_OCT_SIGN[i][j];
    int p0 = (sub >> 2) * 64, q0 = (sub & 3) * 64;
    float inv_s = 1.0f / (*sptr);
#pragma unroll
    for (int pass = 0; pass < 4; pass++) {
        int p = p0 + pass * 16 + (tid >> 4);
        int q = q0 + (tid & 15) * 4;
        float4 wv = *(const float4*)&W[i * 65536 + p * 256 + q];
        float* Tp = &Tt[(pass * 16 + (tid >> 4)) * 68 + (tid & 15) * 4];
        Tp[0] = sign * rintf(fminf(1.f, fmaxf(-1.f, wv.x * inv_s)));
        Tp[1] = sign * rintf(fminf(1.f, fmaxf(-1.f, wv.y * inv_s)));
        Tp[2] = sign * rintf(fminf(1.f, fmaxf(-1.f, wv.z * inv_s)));
        Tp[3] = sign * rintf(fminf(1.f, fmaxf(-1.f, wv.w * inv_s)));
    }
    __syncthreads();
#pragma unroll
    for (int pass = 0; pass < 2; pass++) {
        int qq = pass * 32 + (tid >> 3);
        int pl = (tid & 7) * 8;
        u16 r[8];
#pragma unroll
        for (int l = 0; l < 8; l++) r[l] = f2bf_trunc(Tt[(pl + l) * 68 + qq]);
        uint4 o;
        o.x = pack2(r[0], r[1]); o.y = pack2(r[2], r[3]);
        o.z = pack2(r[4], r[5]); o.w = pack2(r[6], r[7]);
        *(uint4*)&WT[(size_t)(kblk * 256 + q0 + qq) * 2048 + j * 256 + p0 + pl] = o;
    }
}

// ---- GEMM: C[4096][2048] = s*(A @ WT^T); R3-proven 2-barrier K-loop ----
// MODE 0: rope fused, bf16 row-major (rscale = sm*log2e for Q, 1.0 for K)
// MODE 1: f32 row-major.  MODE 2: bf16 VT[(b*16+h)*128+d][t]
template <int MODE>
__global__ __launch_bounds__(256) void gemm_kernel(
    const u16* __restrict__ A, const u16* __restrict__ Bt,
    const float* __restrict__ sptr, const float* __restrict__ fc,
    const float* __restrict__ fs, float rscale, void* __restrict__ Cout) {
    __shared__ __align__(16) u16 As[128 * 32];
    __shared__ __align__(16) u16 Bs[128 * 32];
    const int K = 2048;
    int tid = threadIdx.x, lane = tid & 63, wid = tid >> 6;
    int quad = lane >> 4, l16 = lane & 15;
    int wm = (wid >> 1) * 64, wn = (wid & 1) * 64;
    int m0 = blockIdx.y * 128, n0 = blockIdx.x * 128;
    f32x4 acc[4][4];
#pragma unroll
    for (int a = 0; a < 4; a++)
#pragma unroll
        for (int b = 0; b < 4; b++) acc[a][b] = (f32x4){0.f, 0.f, 0.f, 0.f};
    int srow = lane >> 2;
    int sblk = (lane & 3) ^ (srow & 3);
    const u16* Ag = A + (size_t)(m0 + wid * 32 + srow) * K + sblk * 8;
    const u16* Bg = Bt + (size_t)(n0 + wid * 32 + srow) * K + sblk * 8;
    u16* Al = &As[(wid * 32) * 32];
    u16* Bl = &Bs[(wid * 32) * 32];
    int rblk = (quad ^ (l16 & 3)) * 8;
    for (int k0 = 0; k0 < K; k0 += 32) {
        __syncthreads();
        async16(Ag + k0, Al);
        async16(Ag + k0 + (size_t)16 * K, Al + 16 * 32);
        async16(Bg + k0, Bl);
        async16(Bg + k0 + (size_t)16 * K, Bl + 16 * 32);
        __syncthreads();
        short8 af[4], bfv[4];
#pragma unroll
        for (int mt = 0; mt < 4; mt++) af[mt] = *(const short8*)&As[(wm + mt * 16 + l16) * 32 + rblk];
#pragma unroll
        for (int nt = 0; nt < 4; nt++) bfv[nt] = *(const short8*)&Bs[(wn + nt * 16 + l16) * 32 + rblk];
#pragma unroll
        for (int mt = 0; mt < 4; mt++)
#pragma unroll
            for (int nt = 0; nt < 4; nt++)
                acc[mt][nt] = __builtin_amdgcn_mfma_f32_16x16x32_bf16(af[mt], bfv[nt], acc[mt][nt], 0, 0, 0);
    }
    float s = sptr[0];
#pragma unroll
    for (int mt = 0; mt < 4; mt++)
#pragma unroll
        for (int nt = 0; nt < 4; nt++) {
            int mg = m0 + wm + mt * 16 + quad * 4;   // +r ; C/D row=quad*4+reg
            int ng = n0 + wn + nt * 16 + l16;        // col=lane&15
            if (MODE == 0) {
                int mi = (ng & 127) >> 1;
#pragma unroll
                for (int r = 0; r < 4; r++) {
                    float v = acc[mt][nt][r] * s;
                    float vp = __shfl_xor(v, 1, 64);  // partner column (ng^1): lane^1
                    int t = mg + r;
                    int tm = t & 2047;                // position within batch (fc/fs are [2048][64])
                    float cs = fc[tm * 64 + mi] * rscale;
                    float sn = fs[tm * 64 + mi] * rscale;
                    if (!(ng & 1)) {   // even lane stores the pair as one dword
                        u32 pk = pack2(f2bf(v * cs - vp * sn), f2bf(v * sn + vp * cs));
                        ((u32*)Cout)[((size_t)t * 2048 + ng) >> 1] = pk;
                    }
                }
            } else if (MODE == 1) {
#pragma unroll
                for (int r = 0; r < 4; r++)
                    ((float*)Cout)[(size_t)(mg + r) * 2048 + ng] = acc[mt][nt][r] * s;
            } else {
                ushort4 o4;
                o4.x = f2bf(acc[mt][nt][0] * s);
                o4.y = f2bf(acc[mt][nt][1] * s);
                o4.z = f2bf(acc[mt][nt][2] * s);
                o4.w = f2bf(acc[mt][nt][3] * s);
                // VT[(b*16+h)*128 + d][t], 4 consecutive t
                *(ushort4*)&((u16*)Cout)[((size_t)((mg >> 11) * 16 + (ng >> 7)) * 128 + (ng & 127)) * 2048 + (mg & 2047)] = o4;
            }
        }
}

// ---- flash: 128-row Q tiles, 4 waves x 32 q-rows, dbuf K/V, wave-private P ----
// Q,K row-major (Q pre-scaled+roped); VT [(b*16+h)*128+d][t]; Y row-major bf16 (aliases Q)
__global__ __launch_bounds__(256, 2) void flash_kernel(
    const u16* __restrict__ Q, const u16* __restrict__ Kg,
    const u16* __restrict__ VTg, u16* __restrict__ Y) {
    __shared__ __align__(16) u16 Ks[2][64 * 128];   // [key][d], XOR-swizzled (16 KB each)
    __shared__ __align__(16) u16 Vs[2][128 * 64];   // [d][key], XOR-swizzled (16 KB each)
    __shared__ __align__(16) u16 Ps[128 * 64];      // wave-private P rows [wid*32..wid*32+31] (16 KB)
    int tid = threadIdx.x, lane = tid & 63, wid = tid >> 6;   // 4 waves
    int quad = lane >> 4, l16 = lane & 15;
    int bh = blockIdx.x, b = bh >> 4, h = bh & 15;            // x=bh: head's K/V pinned to one XCD
    int qt = 15 - blockIdx.y;                                 // LPT: longest tiles dispatched first
    int nit = 2 * (qt + 1);
    int q0 = qt * 128;
    int wrow = wid * 32;
    const u16* Qb = Q + (size_t)b * 2048 * 2048 + h * 128;
    const u16* Kb = Kg + (size_t)b * 2048 * 2048 + h * 128;
    const u16* Vb = VTg + (size_t)bh * 128 * 2048;
    int krow = lane >> 4, kblk = lane & 15;   // K chunk: 4 rows x 16 blocks
    int vrow = lane >> 3, vblk = lane & 7;    // V chunk: 8 rows x 8 blocks
    // prologue: key tile 0 -> buf 0
#pragma unroll
    for (int cc = 0; cc < 4; cc++) {
        int ch = wid * 4 + cc;
        int kr = ch * 4 + krow;
        async16(&Kb[(size_t)kr * 2048 + (kblk ^ (kr & 15)) * 8], &Ks[0][ch * 512]);
        int vd = ch * 8 + vrow;
        async16(&Vb[(size_t)vd * 2048 + (vblk ^ (vd & 7)) * 8], &Vs[0][ch * 512]);
    }
    short8 qf[2][4];
#pragma unroll
    for (int mt = 0; mt < 2; mt++)
#pragma unroll
        for (int kt = 0; kt < 4; kt++)
            qf[mt][kt] = *(const short8*)&Qb[(size_t)(q0 + wrow + mt * 16 + l16) * 2048 + kt * 32 + quad * 8];
    f32x4 o[2][8];
#pragma unroll
    for (int mt = 0; mt < 2; mt++)
#pragma unroll
        for (int nt = 0; nt < 8; nt++) o[mt][nt] = (f32x4){0.f, 0.f, 0.f, 0.f};
    float m_[2][4], l_[2][4], alpha[2][4];
#pragma unroll
    for (int mt = 0; mt < 2; mt++)
#pragma unroll
        for (int r = 0; r < 4; r++) { m_[mt][r] = -1e30f; l_[mt][r] = 0.f; }
    for (int il = 0; il < nit; il++) {
        int c = il & 1;
        __syncthreads();   // drains prefetch issued one full iter ago; orders buf reuse
        if (il + 1 < nit) {
            int s0n = (il + 1) * 64;
#pragma unroll
            for (int cc = 0; cc < 4; cc++) {
                int ch = wid * 4 + cc;
                int kr = ch * 4 + krow;
                async16(&Kb[(size_t)(s0n + kr) * 2048 + (kblk ^ (kr & 15)) * 8], &Ks[1 - c][ch * 512]);
                int vd = ch * 8 + vrow;
                async16(&Vb[(size_t)vd * 2048 + s0n + (vblk ^ (vd & 7)) * 8], &Vs[1 - c][ch * 512]);
            }
        }
        int s0 = il * 64;
        // S = Q K^T : 32 q-rows x 64 keys per wave (bfv shared across both m-subtiles)
        f32x4 sc[2][4];
#pragma unroll
        for (int ct = 0; ct < 4; ct++) {
            short8 bfv[4];
#pragma unroll
            for (int kt = 0; kt < 4; kt++)
                bfv[kt] = *(const short8*)&Ks[c][(ct * 16 + l16) * 128 + ((kt * 4 + quad) ^ l16) * 8];
#pragma unroll
            for (int mt = 0; mt < 2; mt++) {
                f32x4 a = (f32x4){0.f, 0.f, 0.f, 0.f};
#pragma unroll
                for (int kt = 0; kt < 4; kt++)
                    a = __builtin_amdgcn_mfma_f32_16x16x32_bf16(qf[mt][kt], bfv[kt], a, 0, 0, 0);
                sc[mt][ct] = a;
            }
        }
        if (il >= nit - 2) {   // last two key tiles carry the causal boundary
#pragma unroll
            for (int mt = 0; mt < 2; mt++)
#pragma unroll
                for (int ct = 0; ct < 4; ct++) {
                    int colg = s0 + ct * 16 + l16;
#pragma unroll
                    for (int r = 0; r < 4; r++) {
                        int rowg = q0 + wrow + mt * 16 + quad * 4 + r;
                        if (colg > rowg) sc[mt][ct][r] = -1e30f;
                    }
                }
        }
        u16* Pw = &Ps[wid * 2048];
#pragma unroll
        for (int mt = 0; mt < 2; mt++)
#pragma unroll
            for (int r = 0; r < 4; r++) {
                float mx = fmaxf(fmaxf(sc[mt][0][r], sc[mt][1][r]), fmaxf(sc[mt][2][r], sc[mt][3][r]));
#pragma unroll
                for (int off = 1; off < 16; off <<= 1) mx = fmaxf(mx, __shfl_xor(mx, off, 64));
                float mn = fmaxf(m_[mt][r], mx);
                float al = exp2f(m_[mt][r] - mn);
                float rs = 0.f;
#pragma unroll
                for (int ct = 0; ct < 4; ct++) {
                    float p = exp2f(sc[mt][ct][r] - mn);
                    sc[mt][ct][r] = p;
                    rs += p;
                }
#pragma unroll
                for (int off = 1; off < 16; off <<= 1) rs += __shfl_xor(rs, off, 64);
                m_[mt][r] = mn;
                l_[mt][r] = l_[mt][r] * al + rs;
                alpha[mt][r] = al;
                // P: C-layout -> wave-private LDS (in-wave lgkm ordering, no barrier)
                int lr = mt * 16 + quad * 4 + r;
#pragma unroll
                for (int ct = 0; ct < 4; ct++) {
                    int key = ct * 16 + l16;
                    Pw[lr * 64 + ((key >> 3) ^ (lr & 7)) * 8 + (key & 7)] = f2bf_trunc(sc[mt][ct][r]);
                }
            }
#pragma unroll
        for (int mt = 0; mt < 2; mt++)
#pragma unroll
            for (int nt = 0; nt < 8; nt++)
#pragma unroll
                for (int r = 0; r < 4; r++) o[mt][nt][r] *= alpha[mt][r];
        // O += P V
#pragma unroll
        for (int kt2 = 0; kt2 < 2; kt2++) {
            short8 pa[2];
#pragma unroll
            for (int mt = 0; mt < 2; mt++)
                pa[mt] = *(const short8*)&Pw[(mt * 16 + l16) * 64 + ((kt2 * 4 + quad) ^ (l16 & 7)) * 8];
#pragma unroll
            for (int nt = 0; nt < 8; nt++) {
                short8 vb = *(const short8*)&Vs[c][(nt * 16 + l16) * 64 + ((kt2 * 4 + quad) ^ (l16 & 7)) * 8];
#pragma unroll
                for (int mt = 0; mt < 2; mt++)
                    o[mt][nt] = __builtin_amdgcn_mfma_f32_16x16x32_bf16(pa[mt], vb, o[mt][nt], 0, 0, 0);
            }
        }
    }
#pragma unroll
    for (int mt = 0; mt < 2; mt++) {
        float iv[4];
#pragma unroll
        for (int r = 0; r < 4; r++) iv[r] = 1.f / l_[mt][r];
#pragma unroll
        for (int nt = 0; nt < 8; nt++)
#pragma unroll
            for (int r = 0; r < 4; r++) {
                int t_ = q0 + wrow + mt * 16 + quad * 4 + r;
                Y[((size_t)(b * 2048 + t_)) * 2048 + h * 128 + nt * 16 + l16] = f2bf(o[mt][nt][r] * iv[r]);
            }
    }
}

extern "C" void kernel_launch(void* const* d_in, const int* in_sizes, int n_in,
                              void* d_out, int out_size, void* d_ws, size_t ws_size,
                              hipStream_t stream) {
    const float* x  = (const float*)d_in[0];
    const float* wq = (const float*)d_in[1];
    const float* wk = (const float*)d_in[2];
    const float* wv = (const float*)d_in[3];
    const float* wo = (const float*)d_in[4];
    const float* fc = (const float*)d_in[5];
    const float* fs = (const float*)d_in[6];
    float* out = (float*)d_out;

    char* ws = (char*)d_ws;
    float* s_vals   = (float*)ws;
    float* partials = (float*)(ws + 1024);
    u16* WT  = (u16*)(ws + 8192);
    u16* xb  = (u16*)(ws + 8192 + 8388608);
    u16* Qb  = xb + 8388608;
    u16* Kb  = Qb + 8388608;
    u16* VTb = Kb + 8388608;

    const float QSCALE = 0.08838834764831845f * 1.4426950408889634f;  // 1/sqrt(128)*log2(e)

    reduce1_kernel<<<256, 256, 0, stream>>>(wq, wk, wv, wo, partials);
    reduce2_kernel<<<1, 256, 0, stream>>>(partials, s_vals);
    cast_bf16_kernel<<<4096, 256, 0, stream>>>(x, xb);

    build_weff_kernel<<<1024, 256, 0, stream>>>(wq, s_vals + 0, WT);
    gemm_kernel<0><<<dim3(16, 32), 256, 0, stream>>>(xb, WT, s_vals + 0, fc, fs, QSCALE, Qb);

    build_weff_kernel<<<1024, 256, 0, stream>>>(wk, s_vals + 1, WT);
    gemm_kernel<0><<<dim3(16, 32), 256, 0, stream>>>(xb, WT, s_vals + 1, fc, fs, 1.0f, Kb);

    build_weff_kernel<<<1024, 256, 0, stream>>>(wv, s_vals + 2, WT);
    gemm_kernel<2><<<dim3(16, 32), 256, 0, stream>>>(xb, WT, s_vals + 2, fc, fs, 0.f, VTb);

    flash_kernel<<<dim3(32, 16), 256, 0, stream>>>(Qb, Kb, VTb, Qb /* Y aliases Q: disjoint rows */);

    build_weff_kernel<<<1024, 256, 0, stream>>>(wo, s_vals + 3, WT);
    gemm_kernel<1><<<dim3(16, 32), 256, 0, stream>>>(Qb, WT, s_vals + 3, fc, fs, 0.f, (void*)out);
}

// Round 8
// 437.898 us; speedup vs baseline: 1.0389x; 1.0040x over previous
//
#include <hip/hip_runtime.h>

// B=2, T=2048, C=2048, H=16, HD=128, P=256
// s=mean|W| -> WT ternary bf16 [n][k] -> 2-barrier bf16 GEMMs (Q,K: rope fused; V: transposed)
// -> flash: 128-row Q tiles, 4 waves x 32 rows, dbuf K/V, complementary-qt balanced grid -> out GEMM

typedef __attribute__((ext_vector_type(8))) short short8;
typedef __attribute__((ext_vector_type(4))) float f32x4;
typedef unsigned short u16;
typedef unsigned int u32;

__device__ __forceinline__ float bf2f(u16 u) {
    u32 x = ((u32)u) << 16;
    return __builtin_bit_cast(float, x);
}
__device__ __forceinline__ u16 f2bf(float f) {
    u32 x = __builtin_bit_cast(u32, f);
    x += 0x7fffu + ((x >> 16) & 1u);   // RNE
    return (u16)(x >> 16);
}
__device__ __forceinline__ u16 f2bf_trunc(float f) {
    return (u16)(__builtin_bit_cast(u32, f) >> 16);
}
__device__ __forceinline__ u32 pack2(u16 a, u16 b) { return (u32)a | ((u32)b << 16); }

__device__ __forceinline__ void async16(const void* g, void* l) {
    __builtin_amdgcn_global_load_lds((const __attribute__((address_space(1))) u32*)g,
                                     (__attribute__((address_space(3))) u32*)l, 16, 0, 0);
}

__device__ const int d_OCT_IDX[8][8] = {
    {0,1,2,3,4,5,6,7},{1,0,3,2,5,4,7,6},{2,3,0,1,6,7,4,5},{3,2,1,0,7,6,5,4},
    {4,5,6,7,0,1,2,3},{5,4,7,6,1,0,3,2},{6,7,4,5,2,3,0,1},{7,6,5,4,3,2,1,0}};
__device__ const float d_OCT_SIGN[8][8] = {
    { 1, 1, 1, 1, 1, 1, 1, 1},{ 1,-1, 1,-1, 1,-1,-1, 1},{ 1,-1,-1, 1, 1, 1,-1,-1},
    { 1, 1,-1,-1, 1,-1, 1,-1},{ 1,-1,-1,-1,-1, 1, 1, 1},{ 1, 1,-1, 1,-1,-1,-1, 1},
    { 1, 1, 1,-1,-1, 1,-1,-1},{ 1,-1, 1, 1,-1,-1, 1,-1}};

// ---- stage 1: 64 partial |W| sums per weight ----
__global__ __launch_bounds__(256) void reduce1_kernel(
    const float* __restrict__ w0, const float* __restrict__ w1,
    const float* __restrict__ w2, const float* __restrict__ w3,
    float* __restrict__ partials) {
    int bid = blockIdx.x, wsel = bid >> 6, part = bid & 63;
    const float* W = wsel == 0 ? w0 : wsel == 1 ? w1 : wsel == 2 ? w2 : w3;
    int base = part * 8192 + threadIdx.x;
    float acc = 0.f;
#pragma unroll
    for (int k = 0; k < 32; k++) acc += fabsf(W[base + k * 256]);
#pragma unroll
    for (int off = 1; off < 64; off <<= 1) acc += __shfl_xor(acc, off, 64);
    __shared__ float r4[4];
    if ((threadIdx.x & 63) == 0) r4[threadIdx.x >> 6] = acc;
    __syncthreads();
    if (threadIdx.x == 0) partials[bid] = r4[0] + r4[1] + r4[2] + r4[3];
}
__global__ __launch_bounds__(256) void reduce2_kernel(const float* __restrict__ partials,
                                                      float* __restrict__ s_vals) {
    int w = threadIdx.x >> 6, lane = threadIdx.x & 63;
    float v = partials[w * 64 + lane];
#pragma unroll
    for (int off = 1; off < 64; off <<= 1) v += __shfl_xor(v, off, 64);
    if (lane == 0) s_vals[w] = v / 524288.0f + 1e-8f;
}

// ---- x (f32) -> bf16 ----
__global__ __launch_bounds__(256) void cast_bf16_kernel(const float* __restrict__ X, u16* __restrict__ Xb) {
    int gid = blockIdx.x * 256 + threadIdx.x;
    const float4* X4 = (const float4*)X;
    float4 a = X4[gid * 2], b = X4[gid * 2 + 1];
    uint4 o;
    o.x = pack2(f2bf(a.x), f2bf(a.y));
    o.y = pack2(f2bf(a.z), f2bf(a.w));
    o.z = pack2(f2bf(b.x), f2bf(b.y));
    o.w = pack2(f2bf(b.z), f2bf(b.w));
    *(uint4*)&Xb[gid * 8] = o;
}

// ---- WT[n][k]: coalesced via LDS 64x64 tile transpose ----
__global__ __launch_bounds__(256) void build_weff_kernel(
    const float* __restrict__ W, const float* __restrict__ sptr, u16* __restrict__ WT) {
    __shared__ float Tt[64 * 68];
    int tid = threadIdx.x;
    int combo = blockIdx.x >> 4, sub = blockIdx.x & 15;
    int j = combo >> 3, kblk = combo & 7;
    int i = 0;
#pragma unroll
    for (int ii = 0; ii < 8; ii++)
        if (d_OCT_IDX[ii][j] == kblk) i = ii;
    float sign = d_OCT_SIGN[i][j];
    int p0 = (sub >> 2) * 64, q0 = (sub & 3) * 64;
    float inv_s = 1.0f / (*sptr);
#pragma unroll
    for (int pass = 0; pass < 4; pass++) {
        int p = p0 + pass * 16 + (tid >> 4);
        int q = q0 + (tid & 15) * 4;
        float4 wv = *(const float4*)&W[i * 65536 + p * 256 + q];
        float* Tp = &Tt[(pass * 16 + (tid >> 4)) * 68 + (tid & 15) * 4];
        Tp[0] = sign * rintf(fminf(1.f, fmaxf(-1.f, wv.x * inv_s)));
        Tp[1] = sign * rintf(fminf(1.f, fmaxf(-1.f, wv.y * inv_s)));
        Tp[2] = sign * rintf(fminf(1.f, fmaxf(-1.f, wv.z * inv_s)));
        Tp[3] = sign * rintf(fminf(1.f, fmaxf(-1.f, wv.w * inv_s)));
    }
    __syncthreads();
#pragma unroll
    for (int pass = 0; pass < 2; pass++) {
        int qq = pass * 32 + (tid >> 3);
        int pl = (tid & 7) * 8;
        u16 r[8];
#pragma unroll
        for (int l = 0; l < 8; l++) r[l] = f2bf_trunc(Tt[(pl + l) * 68 + qq]);
        uint4 o;
        o.x = pack2(r[0], r[1]); o.y = pack2(r[2], r[3]);
        o.z = pack2(r[4], r[5]); o.w = pack2(r[6], r[7]);
        *(uint4*)&WT[(size_t)(kblk * 256 + q0 + qq) * 2048 + j * 256 + p0 + pl] = o;
    }
}

// ---- GEMM: C[4096][2048] = s*(A @ WT^T); R3-proven 2-barrier K-loop ----
// MODE 0: rope fused, bf16 row-major (rscale = sm*log2e for Q, 1.0 for K)
// MODE 1: f32 row-major.  MODE 2: bf16 VT[(b*16+h)*128+d][t]
template <int MODE>
__global__ __launch_bounds__(256) void gemm_kernel(
    const u16* __restrict__ A, const u16* __restrict__ Bt,
    const float* __restrict__ sptr, const float* __restrict__ fc,
    const float* __restrict__ fs, float rscale, void* __restrict__ Cout) {
    __shared__ __align__(16) u16 As[128 * 32];
    __shared__ __align__(16) u16 Bs[128 * 32];
    const int K = 2048;
    int tid = threadIdx.x, lane = tid & 63, wid = tid >> 6;
    int quad = lane >> 4, l16 = lane & 15;
    int wm = (wid >> 1) * 64, wn = (wid & 1) * 64;
    int m0 = blockIdx.y * 128, n0 = blockIdx.x * 128;
    f32x4 acc[4][4];
#pragma unroll
    for (int a = 0; a < 4; a++)
#pragma unroll
        for (int b = 0; b < 4; b++) acc[a][b] = (f32x4){0.f, 0.f, 0.f, 0.f};
    int srow = lane >> 2;
    int sblk = (lane & 3) ^ (srow & 3);
    const u16* Ag = A + (size_t)(m0 + wid * 32 + srow) * K + sblk * 8;
    const u16* Bg = Bt + (size_t)(n0 + wid * 32 + srow) * K + sblk * 8;
    u16* Al = &As[(wid * 32) * 32];
    u16* Bl = &Bs[(wid * 32) * 32];
    int rblk = (quad ^ (l16 & 3)) * 8;
    for (int k0 = 0; k0 < K; k0 += 32) {
        __syncthreads();
        async16(Ag + k0, Al);
        async16(Ag + k0 + (size_t)16 * K, Al + 16 * 32);
        async16(Bg + k0, Bl);
        async16(Bg + k0 + (size_t)16 * K, Bl + 16 * 32);
        __syncthreads();
        short8 af[4], bfv[4];
#pragma unroll
        for (int mt = 0; mt < 4; mt++) af[mt] = *(const short8*)&As[(wm + mt * 16 + l16) * 32 + rblk];
#pragma unroll
        for (int nt = 0; nt < 4; nt++) bfv[nt] = *(const short8*)&Bs[(wn + nt * 16 + l16) * 32 + rblk];
#pragma unroll
        for (int mt = 0; mt < 4; mt++)
#pragma unroll
            for (int nt = 0; nt < 4; nt++)
                acc[mt][nt] = __builtin_amdgcn_mfma_f32_16x16x32_bf16(af[mt], bfv[nt], acc[mt][nt], 0, 0, 0);
    }
    float s = sptr[0];
#pragma unroll
    for (int mt = 0; mt < 4; mt++)
#pragma unroll
        for (int nt = 0; nt < 4; nt++) {
            int mg = m0 + wm + mt * 16 + quad * 4;   // +r ; C/D row=quad*4+reg
            int ng = n0 + wn + nt * 16 + l16;        // col=lane&15
            if (MODE == 0) {
                int mi = (ng & 127) >> 1;
#pragma unroll
                for (int r = 0; r < 4; r++) {
                    float v = acc[mt][nt][r] * s;
                    float vp = __shfl_xor(v, 1, 64);  // partner column (ng^1): lane^1
                    int t = mg + r;
                    int tm = t & 2047;                // position within batch (fc/fs are [2048][64])
                    float cs = fc[tm * 64 + mi] * rscale;
                    float sn = fs[tm * 64 + mi] * rscale;
                    if (!(ng & 1)) {   // even lane stores the pair as one dword
                        u32 pk = pack2(f2bf(v * cs - vp * sn), f2bf(v * sn + vp * cs));
                        ((u32*)Cout)[((size_t)t * 2048 + ng) >> 1] = pk;
                    }
                }
            } else if (MODE == 1) {
#pragma unroll
                for (int r = 0; r < 4; r++)
                    ((float*)Cout)[(size_t)(mg + r) * 2048 + ng] = acc[mt][nt][r] * s;
            } else {
                ushort4 o4;
                o4.x = f2bf(acc[mt][nt][0] * s);
                o4.y = f2bf(acc[mt][nt][1] * s);
                o4.z = f2bf(acc[mt][nt][2] * s);
                o4.w = f2bf(acc[mt][nt][3] * s);
                // VT[(b*16+h)*128 + d][t], 4 consecutive t
                *(ushort4*)&((u16*)Cout)[((size_t)((mg >> 11) * 16 + (ng >> 7)) * 128 + (ng & 127)) * 2048 + (mg & 2047)] = o4;
            }
        }
}

// ---- flash: 128-row Q tiles, 4 waves x 32 q-rows, dbuf K/V, wave-private P ----
// Grid: y and y+8 are complementary (nit sums to 34) so the two co-resident blocks
// per CU balance exactly under linear round-robin dispatch.
// Q,K row-major (Q pre-scaled+roped); VT [(b*16+h)*128+d][t]; Y row-major bf16 (aliases Q)
__global__ __launch_bounds__(256, 2) void flash_kernel(
    const u16* __restrict__ Q, const u16* __restrict__ Kg,
    const u16* __restrict__ VTg, u16* __restrict__ Y) {
    __shared__ __align__(16) u16 Ks[2][64 * 128];   // [key][d], XOR-swizzled (16 KB each)
    __shared__ __align__(16) u16 Vs[2][128 * 64];   // [d][key], XOR-swizzled (16 KB each)
    __shared__ __align__(16) u16 Ps[128 * 64];      // wave-private P rows [wid*32..wid*32+31] (16 KB)
    int tid = threadIdx.x, lane = tid & 63, wid = tid >> 6;   // 4 waves
    int quad = lane >> 4, l16 = lane & 15;
    int bh = blockIdx.x, b = bh >> 4, h = bh & 15;            // x=bh: head's K/V pinned to one XCD
    int y = blockIdx.y;
    int qt = (y < 8) ? (15 - y) : (y - 8);                    // complementary pairing: nit(y)+nit(y+8)=34
    int nit = 2 * (qt + 1);
    int q0 = qt * 128;
    int wrow = wid * 32;
    const u16* Qb = Q + (size_t)b * 2048 * 2048 + h * 128;
    const u16* Kb = Kg + (size_t)b * 2048 * 2048 + h * 128;
    const u16* Vb = VTg + (size_t)bh * 128 * 2048;
    int krow = lane >> 4, kblk = lane & 15;   // K chunk: 4 rows x 16 blocks
    int vrow = lane >> 3, vblk = lane & 7;    // V chunk: 8 rows x 8 blocks
    // prologue: key tile 0 -> buf 0
#pragma unroll
    for (int cc = 0; cc < 4; cc++) {
        int ch = wid * 4 + cc;
        int kr = ch * 4 + krow;
        async16(&Kb[(size_t)kr * 2048 + (kblk ^ (kr & 15)) * 8], &Ks[0][ch * 512]);
        int vd = ch * 8 + vrow;
        async16(&Vb[(size_t)vd * 2048 + (vblk ^ (vd & 7)) * 8], &Vs[0][ch * 512]);
    }
    short8 qf[2][4];
#pragma unroll
    for (int mt = 0; mt < 2; mt++)
#pragma unroll
        for (int kt = 0; kt < 4; kt++)
            qf[mt][kt] = *(const short8*)&Qb[(size_t)(q0 + wrow + mt * 16 + l16) * 2048 + kt * 32 + quad * 8];
    f32x4 o[2][8];
#pragma unroll
    for (int mt = 0; mt < 2; mt++)
#pragma unroll
        for (int nt = 0; nt < 8; nt++) o[mt][nt] = (f32x4){0.f, 0.f, 0.f, 0.f};
    float m_[2][4], l_[2][4], alpha[2][4];
#pragma unroll
    for (int mt = 0; mt < 2; mt++)
#pragma unroll
        for (int r = 0; r < 4; r++) { m_[mt][r] = -1e30f; l_[mt][r] = 0.f; }
    for (int il = 0; il < nit; il++) {
        int c = il & 1;
        __syncthreads();   // drains prefetch issued one full iter ago; orders buf reuse
        if (il + 1 < nit) {
            int s0n = (il + 1) * 64;
#pragma unroll
            for (int cc = 0; cc < 4; cc++) {
                int ch = wid * 4 + cc;
                int kr = ch * 4 + krow;
                async16(&Kb[(size_t)(s0n + kr) * 2048 + (kblk ^ (kr & 15)) * 8], &Ks[1 - c][ch * 512]);
                int vd = ch * 8 + vrow;
                async16(&Vb[(size_t)vd * 2048 + s0n + (vblk ^ (vd & 7)) * 8], &Vs[1 - c][ch * 512]);
            }
        }
        int s0 = il * 64;
        // S = Q K^T : 32 q-rows x 64 keys per wave (bfv shared across both m-subtiles)
        f32x4 sc[2][4];
#pragma unroll
        for (int ct = 0; ct < 4; ct++) {
            short8 bfv[4];
#pragma unroll
            for (int kt = 0; kt < 4; kt++)
                bfv[kt] = *(const short8*)&Ks[c][(ct * 16 + l16) * 128 + ((kt * 4 + quad) ^ l16) * 8];
#pragma unroll
            for (int mt = 0; mt < 2; mt++) {
                f32x4 a = (f32x4){0.f, 0.f, 0.f, 0.f};
#pragma unroll
                for (int kt = 0; kt < 4; kt++)
                    a = __builtin_amdgcn_mfma_f32_16x16x32_bf16(qf[mt][kt], bfv[kt], a, 0, 0, 0);
                sc[mt][ct] = a;
            }
        }
        if (il >= nit - 2) {   // last two key tiles carry the causal boundary
#pragma unroll
            for (int mt = 0; mt < 2; mt++)
#pragma unroll
                for (int ct = 0; ct < 4; ct++) {
                    int colg = s0 + ct * 16 + l16;
#pragma unroll
                    for (int r = 0; r < 4; r++) {
                        int rowg = q0 + wrow + mt * 16 + quad * 4 + r;
                        if (colg > rowg) sc[mt][ct][r] = -1e30f;
                    }
                }
        }
        u16* Pw = &Ps[wid * 2048];
#pragma unroll
        for (int mt = 0; mt < 2; mt++)
#pragma unroll
            for (int r = 0; r < 4; r++) {
                float mx = fmaxf(fmaxf(sc[mt][0][r], sc[mt][1][r]), fmaxf(sc[mt][2][r], sc[mt][3][r]));
#pragma unroll
                for (int off = 1; off < 16; off <<= 1) mx = fmaxf(mx, __shfl_xor(mx, off, 64));
                float mn = fmaxf(m_[mt][r], mx);
                float al = exp2f(m_[mt][r] - mn);
                float rs = 0.f;
#pragma unroll
                for (int ct = 0; ct < 4; ct++) {
                    float p = exp2f(sc[mt][ct][r] - mn);
                    sc[mt][ct][r] = p;
                    rs += p;
                }
#pragma unroll
                for (int off = 1; off < 16; off <<= 1) rs += __shfl_xor(rs, off, 64);
                m_[mt][r] = mn;
                l_[mt][r] = l_[mt][r] * al + rs;
                alpha[mt][r] = al;
                // P: C-layout -> wave-private LDS (in-wave lgkm ordering, no barrier)
                int lr = mt * 16 + quad * 4 + r;
#pragma unroll
                for (int ct = 0; ct < 4; ct++) {
                    int key = ct * 16 + l16;
                    Pw[lr * 64 + ((key >> 3) ^ (lr & 7)) * 8 + (key & 7)] = f2bf_trunc(sc[mt][ct][r]);
                }
            }
#pragma unroll
        for (int mt = 0; mt < 2; mt++)
#pragma unroll
            for (int nt = 0; nt < 8; nt++)
#pragma unroll
                for (int r = 0; r < 4; r++) o[mt][nt][r] *= alpha[mt][r];
        // O += P V
#pragma unroll
        for (int kt2 = 0; kt2 < 2; kt2++) {
            short8 pa[2];
#pragma unroll
            for (int mt = 0; mt < 2; mt++)
                pa[mt] = *(const short8*)&Pw[(mt * 16 + l16) * 64 + ((kt2 * 4 + quad) ^ (l16 & 7)) * 8];
#pragma unroll
            for (int nt = 0; nt < 8; nt++) {
                short8 vb = *(const short8*)&Vs[c][(nt * 16 + l16) * 64 + ((kt2 * 4 + quad) ^ (l16 & 7)) * 8];
#pragma unroll
                for (int mt = 0; mt < 2; mt++)
                    o[mt][nt] = __builtin_amdgcn_mfma_f32_16x16x32_bf16(pa[mt], vb, o[mt][nt], 0, 0, 0);
            }
        }
    }
#pragma unroll
    for (int mt = 0; mt < 2; mt++) {
        float iv[4];
#pragma unroll
        for (int r = 0; r < 4; r++) iv[r] = 1.f / l_[mt][r];
#pragma unroll
        for (int nt = 0; nt < 8; nt++)
#pragma unroll
            for (int r = 0; r < 4; r++) {
                int t_ = q0 + wrow + mt * 16 + quad * 4 + r;
                Y[((size_t)(b * 2048 + t_)) * 2048 + h * 128 + nt * 16 + l16] = f2bf(o[mt][nt][r] * iv[r]);
            }
    }
}

extern "C" void kernel_launch(void* const* d_in, const int* in_sizes, int n_in,
                              void* d_out, int out_size, void* d_ws, size_t ws_size,
                              hipStream_t stream) {
    const float* x  = (const float*)d_in[0];
    const float* wq = (const float*)d_in[1];
    const float* wk = (const float*)d_in[2];
    const float* wv = (const float*)d_in[3];
    const float* wo = (const float*)d_in[4];
    const float* fc = (const float*)d_in[5];
    const float* fs = (const float*)d_in[6];
    float* out = (float*)d_out;

    char* ws = (char*)d_ws;
    float* s_vals   = (float*)ws;
    float* partials = (float*)(ws + 1024);
    u16* WT  = (u16*)(ws + 8192);
    u16* xb  = (u16*)(ws + 8192 + 8388608);
    u16* Qb  = xb + 8388608;
    u16* Kb  = Qb + 8388608;
    u16* VTb = Kb + 8388608;

    const float QSCALE = 0.08838834764831845f * 1.4426950408889634f;  // 1/sqrt(128)*log2(e)

    reduce1_kernel<<<256, 256, 0, stream>>>(wq, wk, wv, wo, partials);
    reduce2_kernel<<<1, 256, 0, stream>>>(partials, s_vals);
    cast_bf16_kernel<<<4096, 256, 0, stream>>>(x, xb);

    build_weff_kernel<<<1024, 256, 0, stream>>>(wq, s_vals + 0, WT);
    gemm_kernel<0><<<dim3(16, 32), 256, 0, stream>>>(xb, WT, s_vals + 0, fc, fs, QSCALE, Qb);

    build_weff_kernel<<<1024, 256, 0, stream>>>(wk, s_vals + 1, WT);
    gemm_kernel<0><<<dim3(16, 32), 256, 0, stream>>>(xb, WT, s_vals + 1, fc, fs, 1.0f, Kb);

    build_weff_kernel<<<1024, 256, 0, stream>>>(wv, s_vals + 2, WT);
    gemm_kernel<2><<<dim3(16, 32), 256, 0, stream>>>(xb, WT, s_vals + 2, fc, fs, 0.f, VTb);

    flash_kernel<<<dim3(32, 16), 256, 0, stream>>>(Qb, Kb, VTb, Qb /* Y aliases Q: disjoint rows */);

    build_weff_kernel<<<1024, 256, 0, stream>>>(wo, s_vals + 3, WT);
    gemm_kernel<1><<<dim3(16, 32), 256, 0, stream>>>(Qb, WT, s_vals + 3, fc, fs, 0.f, (void*)out);
}